// Round 18
// baseline (120.160 us; speedup 1.0000x reference)
//
#include <hip/hip_runtime.h>
#include <math.h>

// Problem constants (match reference)
#define N_ATOMS 256
#define N_FEAT  128
#define BATCH   8
#define BINS    300
#define INV_STEP 149.5f        // 1/STEP, STEP = 2/(BINS-1)
#define ONE_OVER_2PI 0.15915494309189535f
#define INV_112 0.8928571428571429f   // 1/1.12
#define WIN 2                  // bins beyond |d|=2 contribute < exp(-9)*|basis| ~ 1e-5 << tol
#define WINW 5                 // 2*WIN+1
#define NHIST 4                // privatized histogram copies per node
#define EXPM2 0.13533528323661270f    // e^-2

struct V3 { float x, y, z; };
__device__ __forceinline__ V3 v3sub(V3 a, V3 b) { return {a.x-b.x, a.y-b.y, a.z-b.z}; }
__device__ __forceinline__ float v3dot(V3 a, V3 b) { return a.x*b.x + a.y*b.y + a.z*b.z; }
__device__ __forceinline__ V3 v3cross(V3 a, V3 b) {
    return {a.y*b.z - a.z*b.y, a.z*b.x - a.x*b.z, a.x*b.y - a.y*b.x};
}
__device__ __forceinline__ float clamp1(float x) { return fminf(1.0f, fmaxf(-1.0f, x)); }

// Branchless Cephes asinf: |x|<=0.5 poly; else pi/2 - 2*asin(sqrt((1-|x|)/2)).
__device__ __forceinline__ float asin_fast(float x) {
    float u = fabsf(x);
    bool big = u > 0.5f;
    float z = big ? 0.5f * (1.0f - u) : u * u;
    float s = big ? __builtin_amdgcn_sqrtf(z) : u;  // v_sqrt_f32
    float p = fmaf(z, 4.2163199048e-2f, 2.4181311049e-2f);
    p = fmaf(z, p, 4.5470025998e-2f);
    p = fmaf(z, p, 7.4953002686e-2f);
    p = fmaf(z, p, 1.6666752422e-1f);
    float r = fmaf(s * z, p, s);
    r = big ? (1.5707963267948966f - 2.0f * r) : r;
    return copysignf(r, x);
}

// writhe of segment pair (i,i+1),(j,j+1) from float4-padded LDS coords.
// Direction normalization algebraically removed (4 rsq instead of 8).
__device__ __forceinline__ float writhe_ij(const float4* cs, int i, int j) {
    const float4 qi  = cs[i],   qi1 = cs[i + 1];
    const float4 qj  = cs[j],   qj1 = cs[j + 1];
    V3 pi  = {qi.x,  qi.y,  qi.z};
    V3 pi1 = {qi1.x, qi1.y, qi1.z};
    V3 pj  = {qj.x,  qj.y,  qj.z};
    V3 pj1 = {qj1.x, qj1.y, qj1.z};

    V3 u0 = v3sub(pj,  pi);
    V3 u1 = v3sub(pj1, pi);
    V3 u2 = v3sub(pj,  pi1);
    V3 u3 = v3sub(pj1, pi1);

    V3 c0 = v3cross(u0, u1);
    V3 c1 = v3cross(u1, u3);
    V3 c2 = v3cross(u3, u2);
    V3 c3 = v3cross(u2, u0);

    float r0 = __builtin_amdgcn_rsqf(v3dot(c0, c0));
    float r1 = __builtin_amdgcn_rsqf(v3dot(c1, c1));
    float r2 = __builtin_amdgcn_rsqf(v3dot(c2, c2));
    float r3 = __builtin_amdgcn_rsqf(v3dot(c3, c3));

    float omega = asin_fast(clamp1(v3dot(c0, c1) * (r0 * r1)))
                + asin_fast(clamp1(v3dot(c1, c2) * (r1 * r2)))
                + asin_fast(clamp1(v3dot(c2, c3) * (r2 * r3)))
                + asin_fast(clamp1(v3dot(c3, c0) * (r3 * r0)));

    float sg = v3dot(v3cross(v3sub(pj1, pj), v3sub(pi1, pi)), u0);
    float sign = (sg > 0.0f) ? 1.0f : ((sg < 0.0f) ? -1.0f : 0.0f);
    return omega * sign * ONE_OVER_2PI;
}

// edge -> (g, pp, k0) for node tau, edge index ee (branchless)
__device__ __forceinline__ void edge_compute(const float4* cs, int tau, int ee,
                                             float& g, float& pp, int& k0) {
    const int eT1 = (tau <= N_ATOMS - 2) ? tau - 1 : 0;
    const int typ = (ee < eT1) ? 0 : 1;
    const int a = (typ == 0) ? ee : ee - eT1 + 1;

    const float4 qa = cs[a];
    const float4 qt = cs[tau];
    const float dx = qa.x - qt.x;
    const float dy = qa.y - qt.y;
    const float dz = qa.z - qt.z;
    g = __expf(-(dx*dx + dy*dy + dz*dz));

    const float w = writhe_ij(cs, a - typ, tau - typ);
    pp = (w + 1.0f) * INV_STEP;          // pp - k = (w - c_k)/STEP
    k0 = __float2int_rn(pp);
}

// One 256-thread block per NODE PAIR (t0, t1) = (p+2, 255-p), same batch.
// 2 edges/thread (edge2 = tid+256 is ALWAYS node1 since E0 <= 253).
// TWO barriers only: init(cs load + eager h2 zero) -> BAR -> compute x2 ->
// deposit x2 -> butterfly+leader atomics -> BAR -> project (reads all 4
// copies directly; same-address lanes broadcast) + write.
__global__ __launch_bounds__(256) void fused_kernel(const float* __restrict__ coords,
                                                    const float* __restrict__ nf,
                                                    const float* __restrict__ basis,
                                                    float* __restrict__ out) {
    const int blk = blockIdx.x;
    const int b = blk & 7;
    const int p = blk >> 3;            // pair index 0..126
    const int t0 = p + 2;              // 2..128
    const int t1 = 255 - p;            // 255..129
    const int tid = threadIdx.x;

    const int E0  = 2 * t0 - 3;                         // edges of node t0 (<=253)
    const int E1n = (t1 == 255) ? 253 : 2 * t1 - 3;     // edges of node t1
    const int E = E0 + E1n;                             // 508 (254 when p==0)

    const int nu_out = tid >> 7;       // 0: node t0 row, 1: node t1 row
    const int f_out = tid & 127;
    const int row_out = nu_out ? t1 : t0;
    const float mynf = nf[((size_t)((b << 8) | row_out)) * N_FEAT + f_out];

    __shared__ float4 cs[N_ATOMS];           // 4 KB, padded xyz0
    __shared__ float h2[2 * NHIST * BINS];   // 9.6 KB (two 4-copy histograms)
    __shared__ float sden[2];
    __shared__ int skmin[2], skmax[2];

    // ---- init phase: coords load + eager zero (no dependencies) ----
    {
        const int gbase = ((b << 8) + tid) * 3;
        cs[tid] = make_float4(coords[gbase], coords[gbase + 1], coords[gbase + 2], 0.0f);
    }
    #pragma unroll
    for (int k = tid; k < 2 * NHIST * BINS; k += 256) h2[k] = 0.0f;
    if (tid < 2) { sden[tid] = 0.0f; skmin[tid] = BINS - 1; skmax[tid] = 0; }
    __syncthreads();                         // BARRIER 1

    // ---- two independent edge computations (branchless; ILP) ----
    const bool act1 = (tid < E);                  // p>=1: always true
    const int node1e = (tid < E0) ? 0 : 1;
    const int ee1 = (node1e == 1) ? min(tid - E0, E1n - 1) : tid;
    const int tau1 = node1e ? t1 : t0;

    const bool act2 = (tid + 256 < E);            // edge2 always node 1
    const int ee2 = act2 ? (tid + 256 - E0) : 0;

    float g1, pp1; int k01;
    float g2, pp2; int k02;
    edge_compute(cs, tau1, ee1, g1, pp1, k01);
    edge_compute(cs, t1,   ee2, g2, pp2, k02);

    // ---- deposits (exp-recurrence, g folded into seed) ----
    const int copy = tid & (NHIST - 1);
    if (act1) {
        const int base = (node1e * NHIST + copy) * BINS;
        const int klo = k01 - WIN;
        float d = pp1 - (float)klo;
        float e = g1 * __expf(-d * d);
        float u = __expf(2.0f * d - 1.0f);
        #pragma unroll
        for (int m = 0; m < WINW; ++m) {
            const int k = klo + m;
            if (k >= 0 && k < BINS) atomicAdd(&h2[base + k], e);
            e *= u;
            u *= EXPM2;
        }
    }
    if (act2) {
        const int base = (NHIST + copy) * BINS;  // node 1
        const int klo = k02 - WIN;
        float d = pp2 - (float)klo;
        float e = g2 * __expf(-d * d);
        float u = __expf(2.0f * d - 1.0f);
        #pragma unroll
        for (int m = 0; m < WINW; ++m) {
            const int k = klo + m;
            if (k >= 0 && k < BINS) atomicAdd(&h2[base + k], e);
            e *= u;
            u *= EXPM2;
        }
    }

    // ---- per-node range + denominator reduction (independent of deposits) ----
    float d0 = (act1 && node1e == 0) ? g1 : 0.0f;
    float d1 = ((act1 && node1e == 1) ? g1 : 0.0f) + (act2 ? g2 : 0.0f);
    int kn0 = BINS - 1, kx0 = 0, kn1 = BINS - 1, kx1 = 0;
    if (act1) {
        const int kmn = max(0, k01 - WIN), kmx = min(BINS - 1, k01 + WIN);
        if (node1e == 0) { kn0 = kmn; kx0 = kmx; } else { kn1 = kmn; kx1 = kmx; }
    }
    if (act2) {
        kn1 = min(kn1, max(0, k02 - WIN));
        kx1 = max(kx1, min(BINS - 1, k02 + WIN));
    }

    #pragma unroll
    for (int off = 32; off > 0; off >>= 1) {
        d0 += __shfl_xor(d0, off, 64);
        d1 += __shfl_xor(d1, off, 64);
        kn0 = min(kn0, __shfl_xor(kn0, off, 64));
        kx0 = max(kx0, __shfl_xor(kx0, off, 64));
        kn1 = min(kn1, __shfl_xor(kn1, off, 64));
        kx1 = max(kx1, __shfl_xor(kx1, off, 64));
    }
    if ((tid & 63) == 0) {
        atomicAdd(&sden[0], d0);
        atomicAdd(&sden[1], d1);
        atomicMin(&skmin[0], kn0);
        atomicMax(&skmax[0], kx0);
        atomicMin(&skmin[1], kn1);
        atomicMax(&skmax[1], kx1);
    }
    __syncthreads();                         // BARRIER 2

    // ---- projection + direct write (combine folded in: 4 copies read) ----
    {
        const int kmin = skmin[nu_out], kmax = skmax[nu_out];
        const int base = nu_out * NHIST * BINS;
        float acc = 0.0f;
        for (int k = kmin; k <= kmax; ++k) {
            const float hv = h2[base + k] + h2[base + BINS + k]
                           + h2[base + 2 * BINS + k] + h2[base + 3 * BINS + k];
            acc = fmaf(hv, basis[k * N_FEAT + f_out], acc);
        }
        out[((size_t)((b << 8) | row_out)) * N_FEAT + f_out]
            = mynf + acc * (INV_112 / sden[nu_out]);
    }
    if (p == 0) {
        // passthrough rows t = 0, 1 (no incoming edges), from the (2,255) block
        const size_t idx = ((size_t)((b << 8) | nu_out)) * N_FEAT + f_out;
        out[idx] = nf[idx];
    }
}

extern "C" void kernel_launch(void* const* d_in, const int* in_sizes, int n_in,
                              void* d_out, int out_size, void* d_ws, size_t ws_size,
                              hipStream_t stream) {
    const float* coords = (const float*)d_in[0];   // (B*N, 3) f32
    const float* nf     = (const float*)d_in[1];   // (B*N, 128) f32
    const float* basis  = (const float*)d_in[2];   // (300, 128) f32
    float* out = (float*)d_out;                    // (B*N, 128) f32

    fused_kernel<<<BATCH * 127, 256, 0, stream>>>(coords, nf, basis, out);
}